// Round 1
// baseline (175.420 us; speedup 1.0000x reference)
//
#include <hip/hip_runtime.h>

// Problem constants
#define N_TOTAL   65536   // B*H*W = 64*32*32
#define HW_SZ     1024    // H*W
#define CDIM      64      // embedding dim (= C)
#define K_CODES   1024
#define OUT_ELEMS 4194304 // 64*64*32*32
#define QT        64      // queries per argmin block (was 128)
#define CHUNK     64      // codes per LDS chunk (double-buffered)
#define NCHUNK    (K_CODES / CHUNK)   // 16
#define TAU       0.004f  // rescue margin (> 2x analytic bf16x3 error bound ~1.5e-3)

// ws layout (bytes):
//   0      : enorm[1024]    f32
//   4096   : hist[1024]     u32
//   8192   : partials[1024] f32   (fits the old hole before e_hi)
//   12288  : e_hi[65536] bf16-as-short (128 KB)
//   143360 : e_lo[65536] (128 KB)

typedef __attribute__((ext_vector_type(8))) short short8;
typedef __attribute__((ext_vector_type(4))) float f32x4;

__device__ __forceinline__ unsigned short f2bf(float x) {
    unsigned u = __float_as_uint(x);
    return (unsigned short)((u + 0x7FFFu + ((u >> 16) & 1u)) >> 16);   // RNE
}
__device__ __forceinline__ float bf2f(unsigned short h) {
    return __uint_as_float(((unsigned)h) << 16);
}
__device__ __forceinline__ void gload_lds16(const void* g, void* l) {
    __builtin_amdgcn_global_load_lds(
        (const __attribute__((address_space(1))) void*)g,
        (__attribute__((address_space(3))) void*)l, 16, 0, 0);
}

// ---------------------------------------------------------------- k_prep ----
__global__ void k_prep(const float* __restrict__ emb, float* __restrict__ enorm,
                       short* __restrict__ ehi, short* __restrict__ elo,
                       unsigned int* __restrict__ hist) {
    int gid = blockIdx.x * 256 + threadIdx.x;        // 0..16383
    float4 v = *(const float4*)(emb + gid * 4);
    float s = v.x * v.x + v.y * v.y + v.z * v.z + v.w * v.w;
#pragma unroll
    for (int off = 1; off < 16; off <<= 1) s += __shfl_xor(s, off, 64);
    if ((gid & 15) == 0) enorm[gid >> 4] = s;

    float vv[4] = {v.x, v.y, v.z, v.w};
    short h[4], l[4];
#pragma unroll
    for (int j = 0; j < 4; ++j) {
        unsigned short hh = f2bf(vv[j]);
        h[j] = (short)hh;
        l[j] = (short)f2bf(vv[j] - bf2f(hh));
    }
    *(short4*)&ehi[gid * 4] = make_short4(h[0], h[1], h[2], h[3]);
    *(short4*)&elo[gid * 4] = make_short4(l[0], l[1], l[2], l[3]);

    if (gid < K_CODES) hist[gid] = 0u;
}

// -------------------------------------------------------------- k_argmin ----
// 256 thr = 4 waves; QT=64 queries/block x all 1024 codes, bf16x3 MFMA,
// CHUNK=64 double-buffered async staging. A-fragments are loaded STRAIGHT
// from global into registers (no xs LDS tile) -> LDS ~37.5 KB -> 4 blocks/CU
// (grid 1024 = 4/CU) for 2x occupancy vs the previous version.
// Post-merge, flagged queries (margin < TAU) are re-solved EXACTLY in fp32
// in-block. Epilogue on final indices: hist atomics, SSE partial, transposed
// out-write through an LDS tile aliased over es.
__global__ __launch_bounds__(256, 4)
void k_argmin(const float* __restrict__ x, const float* __restrict__ emb,
              const short* __restrict__ ehi, const short* __restrict__ elo,
              const float* __restrict__ enorm,
              unsigned int* __restrict__ hist, float* __restrict__ partials,
              float* __restrict__ out) {
    __shared__ __align__(16) short es[2][2][CHUNK * CDIM];  // 32 KB; epilogue scratch aliases here
    __shared__ __align__(16) float ens[K_CODES];            // 4 KB (exact fp32 ||e||^2)
    __shared__ float xnorm[QT];
    __shared__ int   nflag;
    __shared__ float wdd[4];
    __shared__ int   wii[4];

    const int tid  = threadIdx.x;
    const int lane = tid & 63;
    const int w    = tid >> 6;
    const int quad = lane >> 4;
    const int col  = lane & 15;

    const int n0  = blockIdx.x * QT;
    const int b   = n0 >> 10;
    const int hw0 = n0 & 1023;        // 64-aligned

    auto stage_async = [&](int chunk, int buf) {
        const int cbS = chunk * (CHUNK * CDIM);
#pragma unroll
        for (int h = 0; h < 2; ++h) {
            const short* tab = h ? elo : ehi;
#pragma unroll
            for (int i = 0; i < 2; ++i) {
                int s   = i * 256 + tid;
                int row = s >> 3, bb = s & 7;
                int g   = bb ^ (row & 7);
                gload_lds16(&tab[cbS + row * 64 + g * 8],
                            (void*)&es[buf][h][s * 8]);
            }
        }
    };

    // kick off chunk 0 + ||e||^2 table while we build A-fragments in regs
    stage_async(0, 0);
    gload_lds16(&enorm[tid * 4], (void*)&ens[tid * 4]);   // 256 x 16B = 4 KB, lane-linear

    // A fragments straight from global (coalesced 64B segments per quad),
    // hi/lo bf16 split in registers; ||x||^2 via shfl (no LDS atomics).
    const float* xb = x + b * (CDIM * HW_SZ) + hw0 + w * 16 + col;
    short8 afr[2][2];     // [kc][hi/lo]
    float nloc = 0.f;
#pragma unroll
    for (int kc = 0; kc < 2; ++kc) {
#pragma unroll
        for (int j = 0; j < 8; ++j) {
            int c = (kc * 4 + quad) * 8 + j;
            float v = xb[c * HW_SZ];
            unsigned short h = f2bf(v);
            afr[kc][0][j] = (short)h;
            afr[kc][1][j] = (short)f2bf(v - bf2f(h));
            nloc = __builtin_fmaf(v, v, nloc);
        }
    }
    nloc += __shfl_xor(nloc, 16, 64);
    nloc += __shfl_xor(nloc, 32, 64);
    if (quad == 0) xnorm[w * 16 + col] = nloc;   // exact fp32 ||x||^2 for query w*16+col

    __syncthreads();   // chunk 0 + ens landed (vmcnt drain at barrier), xnorm visible

    float d1[4], d2[4];
    int   i1[4];
#pragma unroll
    for (int t = 0; t < 4; ++t) { d1[t] = 3.4e38f; d2[t] = 3.4e38f; i1[t] = 0; }

    for (int chunk = 0; chunk < NCHUNK; ++chunk) {
        const int buf = chunk & 1;
        if (chunk) __syncthreads();
        if (chunk + 1 < NCHUNK) stage_async(chunk + 1, buf ^ 1);

#pragma unroll
        for (int ct = 0; ct < 4; ++ct) {
            const int r = ct * 16 + col;
            short8 bfr[2][2];
#pragma unroll
            for (int kc = 0; kc < 2; ++kc) {
                int bb  = kc * 4 + quad;
                int off = r * CDIM + ((bb ^ (r & 7)) << 3);
                bfr[kc][0] = *(const short8*)&es[buf][0][off];
                bfr[kc][1] = *(const short8*)&es[buf][1][off];
            }
            const int mycode = chunk * CHUNK + r;
            const float en   = ens[mycode];

            f32x4 acc = {0.f, 0.f, 0.f, 0.f};
            acc = __builtin_amdgcn_mfma_f32_16x16x32_bf16(afr[0][1], bfr[0][0], acc, 0, 0, 0);
            acc = __builtin_amdgcn_mfma_f32_16x16x32_bf16(afr[0][0], bfr[0][1], acc, 0, 0, 0);
            acc = __builtin_amdgcn_mfma_f32_16x16x32_bf16(afr[0][0], bfr[0][0], acc, 0, 0, 0);
            acc = __builtin_amdgcn_mfma_f32_16x16x32_bf16(afr[1][1], bfr[1][0], acc, 0, 0, 0);
            acc = __builtin_amdgcn_mfma_f32_16x16x32_bf16(afr[1][0], bfr[1][1], acc, 0, 0, 0);
            acc = __builtin_amdgcn_mfma_f32_16x16x32_bf16(afr[1][0], bfr[1][0], acc, 0, 0, 0);
#pragma unroll
            for (int reg = 0; reg < 4; ++reg) {
                float d   = __builtin_fmaf(acc[reg], -2.f, en);
                float d1o = d1[reg];
                d2[reg] = __builtin_amdgcn_fmed3f(d, d1o, d2[reg]);
                d1[reg] = fminf(d, d1o);
                i1[reg] = (d < d1o) ? mycode : i1[reg];
            }
        }
    }

    // reduce across 16 cols per query row (codes ascend with col: lex-min ok)
#pragma unroll
    for (int t = 0; t < 4; ++t) {
        float a1 = d1[t], a2 = d2[t];
        int ai = i1[t];
#pragma unroll
        for (int off = 1; off < 16; off <<= 1) {
            float o1 = __shfl_xor(a1, off, 64);
            float o2 = __shfl_xor(a2, off, 64);
            int   oi = __shfl_xor(ai, off, 64);
            if (o1 < a1 || (o1 == a1 && oi < ai)) {
                float loser = a1; a2 = fminf(fminf(a2, o2), loser); a1 = o1; ai = oi;
            } else {
                a2 = fminf(fminf(a2, o2), o1);
            }
        }
        d1[t] = a1; d2[t] = a2; i1[t] = ai;
    }

    // per-query results -> LDS (alias into es; K-loop reads are done after barrier)
    float* rd1   = (float*)es;                       // bytes 0..255
    float* rd2   = rd1 + QT;                         // 256..511
    int*   ri    = (int*)(rd2 + QT);                 // 512..767
    int*   flist = (int*)((char*)es + 768);          // 768..1023
    float* xqf   = (float*)((char*)es + 1024);       // 1024..1279
    float* tile  = (float*)((char*)es + 1280);       // 1280..19711 (64*72 f32)

    __syncthreads();                                 // all waves done with es K-loop reads
    if (tid == 0) nflag = 0;
    if (col == 0) {
#pragma unroll
        for (int reg = 0; reg < 4; ++reg) {
            int m = w * 16 + quad * 4 + reg;
            rd1[m] = d1[reg];
            rd2[m] = d2[reg];
            ri [m] = i1[reg];
        }
    }
    __syncthreads();

    // flag queries with margin < TAU for exact in-block re-solve
    if (tid < QT) {
        if (rd2[tid] - rd1[tid] < TAU) {
            int slot = atomicAdd(&nflag, 1);
            flist[slot] = tid;
        }
    }
    __syncthreads();

    // ---- in-block exact fp32 rescue (avg nflag ~0-1 per block) ----
    for (int f = 0; f < nflag; ++f) {
        const int q = flist[f];
        if (tid < CDIM) xqf[tid] = x[b * (CDIM * HW_SZ) + tid * HW_SZ + hw0 + q];
        __syncthreads();
        float dm = 3.4e38f; int im = 0;
#pragma unroll
        for (int cd = 0; cd < 4; ++cd) {
            const int k = tid + cd * 256;            // codes ascend with cd
            const float4* er = (const float4*)(emb + k * CDIM);
            const float4* xr = (const float4*)xqf;
            float dot = 0.f;
#pragma unroll
            for (int c4 = 0; c4 < 16; ++c4) {
                float4 e = er[c4], xv = xr[c4];
                dot += e.x * xv.x + e.y * xv.y + e.z * xv.z + e.w * xv.w;
            }
            float d = ens[k] - 2.f * dot;            // exact fp32
            if (d < dm) { dm = d; im = k; }
        }
#pragma unroll
        for (int off = 1; off < 64; off <<= 1) {
            float od = __shfl_xor(dm, off, 64);
            int   oi = __shfl_xor(im, off, 64);
            if (od < dm || (od == dm && oi < im)) { dm = od; im = oi; }
        }
        if (lane == 0) { wdd[w] = dm; wii[w] = im; }
        __syncthreads();
        if (tid == 0) {
            float bd = wdd[0]; int bi = wii[0];
#pragma unroll
            for (int ww = 1; ww < 4; ++ww)
                if (wdd[ww] < bd || (wdd[ww] == bd && wii[ww] < bi)) { bd = wdd[ww]; bi = wii[ww]; }
            rd1[q] = bd; ri[q] = bi;                 // final exact result
        }
        __syncthreads();
    }

    // ---- epilogue on FINAL indices: hist, SSE partial (wave 0) ----
    if (tid < QT) {
        int ai = ri[tid];
        atomicAdd(&hist[ai], 1u);
        float sp = rd1[tid] + xnorm[tid];            // ||q-x||^2 (exact for rescued)
#pragma unroll
        for (int off = 32; off; off >>= 1) sp += __shfl_down(sp, off, 64);
        if (tid == 0) partials[blockIdx.x] = sp;
    }

    // ---- fused output write: gather codes -> LDS tile -> transposed write ----
    {   // gather: thread = (q = tid>>2, j = tid&3) -> 16 channels (reads ri, writes tile: disjoint)
        int q = tid >> 2, j = tid & 3;
        int code = ri[q];
        short8 hi0 = *(const short8*)&ehi[code * CDIM + j * 16];
        short8 hi1 = *(const short8*)&ehi[code * CDIM + j * 16 + 8];
        short8 lo0 = *(const short8*)&elo[code * CDIM + j * 16];
        short8 lo1 = *(const short8*)&elo[code * CDIM + j * 16 + 8];
        float* dst = &tile[q * 72 + j * 16];
#pragma unroll
        for (int k = 0; k < 8; ++k) {
            dst[k]     = bf2f((unsigned short)hi0[k]) + bf2f((unsigned short)lo0[k]);
            dst[8 + k] = bf2f((unsigned short)hi1[k]) + bf2f((unsigned short)lo1[k]);
        }
    }
    __syncthreads();
    {   // transposed coalesced write
        int c = tid >> 2;
        float* ob = out + b * (CDIM * HW_SZ) + c * HW_SZ + hw0;
#pragma unroll
        for (int p = 0; p < 4; ++p) {
            int q = ((tid & 3) + p * 4) * 4;   // 0..60
            float4 v;
            v.x = tile[(q + 0) * 72 + c];
            v.y = tile[(q + 1) * 72 + c];
            v.z = tile[(q + 2) * 72 + c];
            v.w = tile[(q + 3) * 72 + c];
            *(float4*)&ob[q] = v;
        }
    }
}

// --------------------------------------------------------------- k_final ----
// 1 block; reads partials (1024) + hist (1024) from previous dispatches.
__global__ void k_final(const float* __restrict__ partials,
                        const unsigned int* __restrict__ hist,
                        float* __restrict__ out) {
    int tid = threadIdx.x;   // 256
    float ss = 0.f;
#pragma unroll
    for (int i = 0; i < 4; ++i) ss += partials[i * 256 + tid];
    float s = 0.f;
#pragma unroll
    for (int i = 0; i < 4; ++i) {
        float p = (float)hist[i * 256 + tid] * (1.0f / 65536.0f);
        s += p * logf(p + 1e-10f);
    }
    __shared__ float fin[8];
#pragma unroll
    for (int off = 32; off; off >>= 1) {
        ss += __shfl_down(ss, off, 64);
        s  += __shfl_down(s, off, 64);
    }
    if ((tid & 63) == 0) { fin[tid >> 6] = ss; fin[4 + (tid >> 6)] = s; }
    __syncthreads();
    if (tid == 0) {
        float sse = fin[0] + fin[1] + fin[2] + fin[3];
        float ent = fin[4] + fin[5] + fin[6] + fin[7];
        out[OUT_ELEMS]     = 1.25f * sse * (1.0f / (float)OUT_ELEMS);  // loss
        out[OUT_ELEMS + 1] = expf(-ent);                                // perplexity
    }
}

// ---------------------------------------------------------------- launch ----
extern "C" void kernel_launch(void* const* d_in, const int* in_sizes, int n_in,
                              void* d_out, int out_size, void* d_ws, size_t ws_size,
                              hipStream_t stream) {
    const float* x   = (const float*)d_in[0];
    const float* emb = (const float*)d_in[1];
    float* out = (float*)d_out;
    char* ws = (char*)d_ws;
    float*        enorm    = (float*)(ws);
    unsigned int* hist     = (unsigned int*)(ws + 4096);
    float*        partials = (float*)(ws + 8192);
    short*        ehi      = (short*)(ws + 12288);
    short*        elo      = (short*)(ws + 143360);

    k_prep  <<<64, 256, 0, stream>>>(emb, enorm, ehi, elo, hist);
    k_argmin<<<N_TOTAL / QT, 256, 0, stream>>>(x, emb, ehi, elo, enorm, hist, partials, out);
    k_final <<<1, 256, 0, stream>>>(partials, hist, out);
}

// Round 2
// 143.885 us; speedup vs baseline: 1.2192x; 1.2192x over previous
//
#include <hip/hip_runtime.h>

// Problem constants
#define N_TOTAL   65536   // B*H*W = 64*32*32
#define HW_SZ     1024    // H*W
#define CDIM      64      // embedding dim (= C)
#define K_CODES   1024
#define OUT_ELEMS 4194304 // 64*64*32*32
#define QT        128     // queries per argmin block
#define NCT       (K_CODES / 16)   // 64 code-tiles of 16
#define TAU       0.004f  // rescue margin (> 2x analytic bf16x3 error bound ~1.5e-3)

// ws layout (bytes):
//   0      : enorm[1024]   f32
//   4096   : hist[1024]    u32
//   8192   : partials[512] f32
//   12288  : btab (256 KB) bf16 hi/lo table in MFMA B-FRAGMENT order:
//            short index = ct*2048 + kc*1024 + h*512 + lane*8 + j
//            where code = ct*16 + (lane&15), dim = (kc*4 + (lane>>4))*8 + j,
//            h: 0=hi bf16, 1=lo bf16. A wave's 4 frag loads for one ct are
//            4 coalesced 1KB segments at imm offsets 0/1024/2048/3072 B.

typedef __attribute__((ext_vector_type(8))) short short8;
typedef __attribute__((ext_vector_type(4))) float f32x4;

__device__ __forceinline__ unsigned short f2bf(float x) {
    unsigned u = __float_as_uint(x);
    return (unsigned short)((u + 0x7FFFu + ((u >> 16) & 1u)) >> 16);   // RNE
}
__device__ __forceinline__ float bf2f(unsigned short h) {
    return __uint_as_float(((unsigned)h) << 16);
}
__device__ __forceinline__ void gload_lds16(const void* g, void* l) {
    __builtin_amdgcn_global_load_lds(
        (const __attribute__((address_space(1))) void*)g,
        (__attribute__((address_space(3))) void*)l, 16, 0, 0);
}

// ---------------------------------------------------------------- k_prep ----
// Writes ||e||^2 and the frag-ordered bf16 hi/lo table.
__global__ void k_prep(const float* __restrict__ emb, float* __restrict__ enorm,
                       short* __restrict__ btab, unsigned int* __restrict__ hist) {
    int gid = blockIdx.x * 256 + threadIdx.x;        // 0..16383
    int r  = gid >> 4;           // code 0..1023
    int d0 = (gid & 15) * 4;     // dim base 0..60
    float4 v = *(const float4*)(emb + gid * 4);
    float s = v.x * v.x + v.y * v.y + v.z * v.z + v.w * v.w;
#pragma unroll
    for (int off = 1; off < 16; off <<= 1) s += __shfl_xor(s, off, 64);
    if ((gid & 15) == 0) enorm[r] = s;

    float vv[4] = {v.x, v.y, v.z, v.w};
    short h[4], l[4];
#pragma unroll
    for (int j = 0; j < 4; ++j) {
        unsigned short hh = f2bf(vv[j]);
        h[j] = (short)hh;
        l[j] = (short)f2bf(vv[j] - bf2f(hh));
    }
    // frag-layout destination (see ws comment). d0..d0+3 stay in one 8-dim group.
    int base = (r >> 4) * 2048 + (d0 >> 5) * 1024
             + ((((d0 >> 3) & 3) * 16 + (r & 15)) * 8) + (d0 & 7);
    *(short4*)&btab[base]       = make_short4(h[0], h[1], h[2], h[3]);
    *(short4*)&btab[base + 512] = make_short4(l[0], l[1], l[2], l[3]);

    if (gid < K_CODES) hist[gid] = 0u;
}

// -------------------------------------------------------------- k_argmin ----
// 256 thr = 4 waves; QT=128 queries/block (2 query-tiles of 16 per wave) x all
// 1024 codes. ZERO barriers in the K-loop: B-fragments are read straight from
// the L2-resident frag-ordered table into a 4-deep rotating register buffer.
// bf16x3 MFMA distance, top-2 tracking, TAU-margin exact fp32 in-block rescue,
// fused epilogue (hist, SSE partial, transposed out-write) unchanged.
__global__ __launch_bounds__(256, 2)
void k_argmin(const float* __restrict__ x, const float* __restrict__ emb,
              const short* __restrict__ btab, const float* __restrict__ enorm,
              unsigned int* __restrict__ hist, float* __restrict__ partials,
              float* __restrict__ out) {
    __shared__ __align__(16) float ens[K_CODES];     // 4 KB exact fp32 ||e||^2
    __shared__ float xnorm[QT];
    __shared__ float rd1[QT];
    __shared__ float rd2[QT];
    __shared__ int   ri[QT];
    __shared__ int   flist[QT];
    __shared__ __align__(16) float xqf[CDIM];
    __shared__ __align__(16) float tile[64 * 72];    // 18.4 KB epilogue transpose
    __shared__ float wdd[4];
    __shared__ int   wii[4];
    __shared__ float spw[2];
    __shared__ int   nflag;

    const int tid  = threadIdx.x;
    const int lane = tid & 63;
    const int w    = tid >> 6;
    const int quad = lane >> 4;
    const int col  = lane & 15;

    const int n0  = blockIdx.x * QT;
    const int b   = n0 >> 10;
    const int hw0 = n0 & 1023;        // 128-aligned

    // stage exact ||e||^2 (async, drained by the pre-loop barrier)
    gload_lds16(&enorm[tid * 4], (void*)&ens[tid * 4]);

    // A fragments straight from global (coalesced 64B segments per quad),
    // hi/lo bf16 split in registers; ||x||^2 via shfl.
    const float* xb = x + b * (CDIM * HW_SZ) + hw0 + col;
    short8 afr[2][2][2];     // [rt][kc][hi/lo]
#pragma unroll
    for (int rt = 0; rt < 2; ++rt) {
        float nloc = 0.f;
#pragma unroll
        for (int kc = 0; kc < 2; ++kc) {
#pragma unroll
            for (int j = 0; j < 8; ++j) {
                int c = (kc * 4 + quad) * 8 + j;
                float v = xb[c * HW_SZ + w * 32 + rt * 16];
                unsigned short hh = f2bf(v);
                afr[rt][kc][0][j] = (short)hh;
                afr[rt][kc][1][j] = (short)f2bf(v - bf2f(hh));
                nloc = __builtin_fmaf(v, v, nloc);
            }
        }
        nloc += __shfl_xor(nloc, 16, 64);
        nloc += __shfl_xor(nloc, 32, 64);
        if (quad == 0) xnorm[w * 32 + rt * 16 + col] = nloc;
    }
    __syncthreads();   // ens + xnorm visible

    float d1[8], d2[8];
    int   i1[8];
#pragma unroll
    for (int t = 0; t < 8; ++t) { d1[t] = 3.4e38f; d2[t] = 3.4e38f; i1[t] = 0; }

    const short* bl = btab + lane * 8;   // per-lane 16B base into frag table

    short8 B0[2][2], B1[2][2], B2[2][2], B3[2][2];   // 4-deep rotating prefetch
    auto LDB = [&](short8 (&B)[2][2], int ct) {
        const short8* p = (const short8*)(bl + ct * 2048);
        B[0][0] = p[0];          // kc0 hi
        B[0][1] = p[64];         // kc0 lo
        B[1][0] = p[128];        // kc1 hi
        B[1][1] = p[192];        // kc1 lo
    };
    auto COMP = [&](short8 (&B)[2][2], int ct) {
        const int   mycode = ct * 16 + col;
        const float en     = ens[mycode];
#pragma unroll
        for (int rt = 0; rt < 2; ++rt) {
            f32x4 acc = {0.f, 0.f, 0.f, 0.f};
            acc = __builtin_amdgcn_mfma_f32_16x16x32_bf16(afr[rt][0][1], B[0][0], acc, 0, 0, 0);
            acc = __builtin_amdgcn_mfma_f32_16x16x32_bf16(afr[rt][0][0], B[0][1], acc, 0, 0, 0);
            acc = __builtin_amdgcn_mfma_f32_16x16x32_bf16(afr[rt][0][0], B[0][0], acc, 0, 0, 0);
            acc = __builtin_amdgcn_mfma_f32_16x16x32_bf16(afr[rt][1][1], B[1][0], acc, 0, 0, 0);
            acc = __builtin_amdgcn_mfma_f32_16x16x32_bf16(afr[rt][1][0], B[1][1], acc, 0, 0, 0);
            acc = __builtin_amdgcn_mfma_f32_16x16x32_bf16(afr[rt][1][0], B[1][0], acc, 0, 0, 0);
#pragma unroll
            for (int reg = 0; reg < 4; ++reg) {
                int t = rt * 4 + reg;
                float d   = __builtin_fmaf(acc[reg], -2.f, en);
                float d1o = d1[t];
                d2[t] = __builtin_amdgcn_fmed3f(d, d1o, d2[t]);
                d1[t] = fminf(d, d1o);
                i1[t] = (d < d1o) ? mycode : i1[t];
            }
        }
    };

    LDB(B0, 0); LDB(B1, 1); LDB(B2, 2); LDB(B3, 3);
    for (int ct = 0; ct < 60; ct += 4) {
        COMP(B0, ct    ); LDB(B0, ct + 4);
        COMP(B1, ct + 1); LDB(B1, ct + 5);
        COMP(B2, ct + 2); LDB(B2, ct + 6);
        COMP(B3, ct + 3); LDB(B3, ct + 7);
    }
    COMP(B0, 60); COMP(B1, 61); COMP(B2, 62); COMP(B3, 63);

    // reduce across 16 cols per query row (codes ascend with col: lex-min ok)
#pragma unroll
    for (int t = 0; t < 8; ++t) {
        float a1 = d1[t], a2 = d2[t];
        int ai = i1[t];
#pragma unroll
        for (int off = 1; off < 16; off <<= 1) {
            float o1 = __shfl_xor(a1, off, 64);
            float o2 = __shfl_xor(a2, off, 64);
            int   oi = __shfl_xor(ai, off, 64);
            if (o1 < a1 || (o1 == a1 && oi < ai)) {
                float loser = a1; a2 = fminf(fminf(a2, o2), loser); a1 = o1; ai = oi;
            } else {
                a2 = fminf(fminf(a2, o2), o1);
            }
        }
        d1[t] = a1; d2[t] = a2; i1[t] = ai;
    }

    if (tid == 0) nflag = 0;
    if (col == 0) {
#pragma unroll
        for (int rt = 0; rt < 2; ++rt)
#pragma unroll
            for (int reg = 0; reg < 4; ++reg) {
                int t = rt * 4 + reg;
                int m = w * 32 + rt * 16 + quad * 4 + reg;
                rd1[m] = d1[t];
                rd2[m] = d2[t];
                ri [m] = i1[t];
            }
    }
    __syncthreads();

    // flag queries with margin < TAU for exact in-block re-solve
    if (tid < QT) {
        if (rd2[tid] - rd1[tid] < TAU) {
            int slot = atomicAdd(&nflag, 1);
            flist[slot] = tid;
        }
    }
    __syncthreads();

    // ---- in-block exact fp32 rescue (avg nflag ~0-1 per block) ----
    for (int f = 0; f < nflag; ++f) {
        const int q = flist[f];
        if (tid < CDIM) xqf[tid] = x[b * (CDIM * HW_SZ) + tid * HW_SZ + hw0 + q];
        __syncthreads();
        float dm = 3.4e38f; int im = 0;
#pragma unroll
        for (int cd = 0; cd < 4; ++cd) {
            const int k = tid + cd * 256;            // codes ascend with cd
            const float4* er = (const float4*)(emb + k * CDIM);
            const float4* xr = (const float4*)xqf;
            float dot = 0.f;
#pragma unroll
            for (int c4 = 0; c4 < 16; ++c4) {
                float4 e = er[c4], xv = xr[c4];
                dot += e.x * xv.x + e.y * xv.y + e.z * xv.z + e.w * xv.w;
            }
            float d = ens[k] - 2.f * dot;            // exact fp32
            if (d < dm) { dm = d; im = k; }
        }
#pragma unroll
        for (int off = 1; off < 64; off <<= 1) {
            float od = __shfl_xor(dm, off, 64);
            int   oi = __shfl_xor(im, off, 64);
            if (od < dm || (od == dm && oi < im)) { dm = od; im = oi; }
        }
        if (lane == 0) { wdd[w] = dm; wii[w] = im; }
        __syncthreads();
        if (tid == 0) {
            float bd = wdd[0]; int bi = wii[0];
#pragma unroll
            for (int ww = 1; ww < 4; ++ww)
                if (wdd[ww] < bd || (wdd[ww] == bd && wii[ww] < bi)) { bd = wdd[ww]; bi = wii[ww]; }
            rd1[q] = bd; ri[q] = bi;                 // final exact result
        }
        __syncthreads();
    }

    // ---- epilogue on FINAL indices: hist, SSE partial ----
    if (tid < QT) {
        int ai = ri[tid];
        atomicAdd(&hist[ai], 1u);
        float sp = rd1[tid] + xnorm[tid];            // ||q-x||^2 (exact for rescued)
#pragma unroll
        for (int off = 32; off; off >>= 1) sp += __shfl_down(sp, off, 64);
        if (lane == 0) spw[tid >> 6] = sp;
    }
    __syncthreads();
    if (tid == 0) partials[blockIdx.x] = spw[0] + spw[1];

    // ---- fused output write: two 64-query halves through the LDS tile ----
#pragma unroll
    for (int h = 0; h < 2; ++h) {
        {   // gather from frag-layout table: thread = (q = tid>>2, j = tid&3)
            int q = tid >> 2, j = tid & 3;
            int code = ri[h * 64 + q];
            int ct = code >> 4, cl = code & 15;
            int kc = j >> 1;
            int qa = (2 * j) & 3, qb = (2 * j + 1) & 3;
            const short* tb = btab + ct * 2048 + kc * 1024;
            short8 hi0 = *(const short8*)&tb[(qa * 16 + cl) * 8];        // dims j*16..+7
            short8 hi1 = *(const short8*)&tb[(qb * 16 + cl) * 8];        // dims j*16+8..+15
            short8 lo0 = *(const short8*)&tb[512 + (qa * 16 + cl) * 8];
            short8 lo1 = *(const short8*)&tb[512 + (qb * 16 + cl) * 8];
            float* dst = &tile[q * 72 + j * 16];
#pragma unroll
            for (int k = 0; k < 8; ++k) {
                dst[k]     = bf2f((unsigned short)hi0[k]) + bf2f((unsigned short)lo0[k]);
                dst[8 + k] = bf2f((unsigned short)hi1[k]) + bf2f((unsigned short)lo1[k]);
            }
        }
        __syncthreads();
        {   // transposed coalesced write
            int c = tid >> 2;
            float* ob = out + b * (CDIM * HW_SZ) + c * HW_SZ + hw0 + h * 64;
#pragma unroll
            for (int p = 0; p < 4; ++p) {
                int q = ((tid & 3) + p * 4) * 4;   // 0..60
                float4 v;
                v.x = tile[(q + 0) * 72 + c];
                v.y = tile[(q + 1) * 72 + c];
                v.z = tile[(q + 2) * 72 + c];
                v.w = tile[(q + 3) * 72 + c];
                *(float4*)&ob[q] = v;
            }
        }
        if (h == 0) __syncthreads();
    }
}

// --------------------------------------------------------------- k_final ----
// 1 block; reads partials (512) + hist (1024) from previous dispatches.
__global__ void k_final(const float* __restrict__ partials,
                        const unsigned int* __restrict__ hist,
                        float* __restrict__ out) {
    int tid = threadIdx.x;   // 256
    float ss = 0.f;
#pragma unroll
    for (int i = 0; i < 2; ++i) ss += partials[i * 256 + tid];
    float s = 0.f;
#pragma unroll
    for (int i = 0; i < 4; ++i) {
        float p = (float)hist[i * 256 + tid] * (1.0f / 65536.0f);
        s += p * logf(p + 1e-10f);
    }
    __shared__ float fin[8];
#pragma unroll
    for (int off = 32; off; off >>= 1) {
        ss += __shfl_down(ss, off, 64);
        s  += __shfl_down(s, off, 64);
    }
    if ((tid & 63) == 0) { fin[tid >> 6] = ss; fin[4 + (tid >> 6)] = s; }
    __syncthreads();
    if (tid == 0) {
        float sse = fin[0] + fin[1] + fin[2] + fin[3];
        float ent = fin[4] + fin[5] + fin[6] + fin[7];
        out[OUT_ELEMS]     = 1.25f * sse * (1.0f / (float)OUT_ELEMS);  // loss
        out[OUT_ELEMS + 1] = expf(-ent);                                // perplexity
    }
}

// ---------------------------------------------------------------- launch ----
extern "C" void kernel_launch(void* const* d_in, const int* in_sizes, int n_in,
                              void* d_out, int out_size, void* d_ws, size_t ws_size,
                              hipStream_t stream) {
    const float* x   = (const float*)d_in[0];
    const float* emb = (const float*)d_in[1];
    float* out = (float*)d_out;
    char* ws = (char*)d_ws;
    float*        enorm    = (float*)(ws);
    unsigned int* hist     = (unsigned int*)(ws + 4096);
    float*        partials = (float*)(ws + 8192);
    short*        btab     = (short*)(ws + 12288);

    k_prep  <<<64, 256, 0, stream>>>(emb, enorm, btab, hist);
    k_argmin<<<N_TOTAL / QT, 256, 0, stream>>>(x, emb, btab, enorm, hist, partials, out);
    k_final <<<1, 256, 0, stream>>>(partials, hist, out);
}

// Round 3
// 132.334 us; speedup vs baseline: 1.3256x; 1.0873x over previous
//
#include <hip/hip_runtime.h>

// Problem constants
#define N_TOTAL   65536   // B*H*W = 64*32*32
#define HW_SZ     1024    // H*W
#define CDIM      64      // embedding dim (= C)
#define K_CODES   1024
#define OUT_ELEMS 4194304 // 64*64*32*32
#define QT        256     // queries per argmin block (64 per wave, rt=4)
#define NCHUNK    4       // 4 chunks of 256 codes (64 KB each), double-buffered
#define TAU       0.004f  // rescue margin (> 2x analytic bf16x3 error bound ~1.5e-3)

// ws layout (bytes):
//   0      : enorm[1024]   f32
//   4096   : hist[1024]    u32
//   8192   : partials[256] f32
//   12288  : btab (256 KB) bf16 hi/lo table in MFMA B-FRAGMENT order:
//            short index = ct*2048 + kc*1024 + h*512 + lane*8 + j
//            where code = ct*16 + (lane&15), dim = (kc*4 + (lane>>4))*8 + j,
//            h: 0=hi bf16, 1=lo bf16.

typedef __attribute__((ext_vector_type(8))) short short8;
typedef __attribute__((ext_vector_type(4))) float f32x4;

__device__ __forceinline__ unsigned short f2bf(float x) {
    unsigned u = __float_as_uint(x);
    return (unsigned short)((u + 0x7FFFu + ((u >> 16) & 1u)) >> 16);   // RNE
}
__device__ __forceinline__ float bf2f(unsigned short h) {
    return __uint_as_float(((unsigned)h) << 16);
}
__device__ __forceinline__ void gload_lds16(const void* g, void* l) {
    __builtin_amdgcn_global_load_lds(
        (const __attribute__((address_space(1))) void*)g,
        (__attribute__((address_space(3))) void*)l, 16, 0, 0);
}

// ---------------------------------------------------------------- k_prep ----
// Writes ||e||^2 and the frag-ordered bf16 hi/lo table.
__global__ void k_prep(const float* __restrict__ emb, float* __restrict__ enorm,
                       short* __restrict__ btab, unsigned int* __restrict__ hist) {
    int gid = blockIdx.x * 256 + threadIdx.x;        // 0..16383
    int r  = gid >> 4;           // code 0..1023
    int d0 = (gid & 15) * 4;     // dim base 0..60
    float4 v = *(const float4*)(emb + gid * 4);
    float s = v.x * v.x + v.y * v.y + v.z * v.z + v.w * v.w;
#pragma unroll
    for (int off = 1; off < 16; off <<= 1) s += __shfl_xor(s, off, 64);
    if ((gid & 15) == 0) enorm[r] = s;

    float vv[4] = {v.x, v.y, v.z, v.w};
    short h[4], l[4];
#pragma unroll
    for (int j = 0; j < 4; ++j) {
        unsigned short hh = f2bf(vv[j]);
        h[j] = (short)hh;
        l[j] = (short)f2bf(vv[j] - bf2f(hh));
    }
    // frag-layout destination (see ws comment). d0..d0+3 stay in one 8-dim group.
    int base = (r >> 4) * 2048 + (d0 >> 5) * 1024
             + ((((d0 >> 3) & 3) * 16 + (r & 15)) * 8) + (d0 & 7);
    *(short4*)&btab[base]       = make_short4(h[0], h[1], h[2], h[3]);
    *(short4*)&btab[base + 512] = make_short4(l[0], l[1], l[2], l[3]);

    if (gid < K_CODES) hist[gid] = 0u;
}

// -------------------------------------------------------------- k_argmin ----
// 256 thr = 4 waves; QT=256 queries/block (4 query-tiles of 16 per wave) x all
// 1024 codes. Code table is LDS-RESIDENT in 4 double-buffered chunks of 256
// codes (64 KB); 2 barriers per chunk, stage of chunk c+1 overlaps compute of
// chunk c. K-loop B reads are ds_read_b128 (compiler-pipelined lgkmcnt), NOT
// per-wave L2 streams. bf16x3 MFMA distance, top-2 tracking, TAU-margin exact
// fp32 in-block rescue, fused epilogue (hist, SSE partial, transposed write).
__global__ __launch_bounds__(256, 1)
void k_argmin(const float* __restrict__ x, const float* __restrict__ emb,
              const short* __restrict__ btab, const float* __restrict__ enorm,
              unsigned int* __restrict__ hist, float* __restrict__ partials,
              float* __restrict__ out) {
    __shared__ __align__(16) short bufs[2][16 * 2048];   // 2 x 64 KB chunk buffers
    __shared__ __align__(16) float ens[K_CODES];         // 4 KB exact fp32 ||e||^2
    __shared__ float xnorm[QT];
    __shared__ float rd1[QT];
    __shared__ float rd2[QT];
    __shared__ int   ri[QT];
    __shared__ int   flist[QT];
    __shared__ __align__(16) float xqf[CDIM];
    __shared__ float wdd[4];
    __shared__ int   wii[4];
    __shared__ float spw[4];
    __shared__ int   nflag;
    float* tile = (float*)bufs;      // 64*72 f32 epilogue transpose, aliases bufs

    const int tid  = threadIdx.x;
    const int lane = tid & 63;
    const int w    = tid >> 6;
    const int quad = lane >> 4;
    const int col  = lane & 15;

    const int n0  = blockIdx.x * QT;
    const int b   = n0 >> 10;
    const int hw0 = n0 & 1023;        // 256-aligned

    auto stage_async = [&](int c, int bsel) {
        const short* src = btab + c * (16 * 2048);
#pragma unroll
        for (int i = 0; i < 16; ++i) {
            int idx = i * 256 + tid;                  // 16B units, 0..4095
            gload_lds16(&src[idx * 8], (void*)&bufs[bsel][idx * 8]);
        }
    };

    // kick off chunk 0 + ||e||^2 while we build A-fragments in registers
    stage_async(0, 0);
    gload_lds16(&enorm[tid * 4], (void*)&ens[tid * 4]);

    // A fragments straight from global; hi/lo bf16 split in regs; ||x||^2 via shfl.
    const float* xb = x + b * (CDIM * HW_SZ) + hw0 + col;
    short8 afr[4][2][2];     // [rt][kc][hi/lo]
#pragma unroll
    for (int rt = 0; rt < 4; ++rt) {
        float nloc = 0.f;
#pragma unroll
        for (int kc = 0; kc < 2; ++kc) {
#pragma unroll
            for (int j = 0; j < 8; ++j) {
                int c0 = (kc * 4 + quad) * 8 + j;
                float v = xb[c0 * HW_SZ + w * 64 + rt * 16];
                unsigned short hh = f2bf(v);
                afr[rt][kc][0][j] = (short)hh;
                afr[rt][kc][1][j] = (short)f2bf(v - bf2f(hh));
                nloc = __builtin_fmaf(v, v, nloc);
            }
        }
        nloc += __shfl_xor(nloc, 16, 64);
        nloc += __shfl_xor(nloc, 32, 64);
        if (quad == 0) xnorm[w * 64 + rt * 16 + col] = nloc;
    }

    float d1[16], d2[16];
    int   i1[16];
#pragma unroll
    for (int t = 0; t < 16; ++t) { d1[t] = 3.4e38f; d2[t] = 3.4e38f; i1[t] = 0; }

    __syncthreads();   // chunk 0 + ens + xnorm ready

    for (int c = 0; c < NCHUNK; ++c) {
        if (c + 1 < NCHUNK) stage_async(c + 1, (c + 1) & 1);   // other buffer is free
        const short* bs = &bufs[c & 1][0];
        const int cbase = c * 256;
#pragma unroll 4
        for (int ctl = 0; ctl < 16; ++ctl) {
            const short* fp = bs + ctl * 2048 + lane * 8;
            short8 B00 = *(const short8*)(fp);            // kc0 hi
            short8 B01 = *(const short8*)(fp + 512);      // kc0 lo
            short8 B10 = *(const short8*)(fp + 1024);     // kc1 hi
            short8 B11 = *(const short8*)(fp + 1536);     // kc1 lo
            const int   mycode = cbase + ctl * 16 + col;
            const float en     = ens[mycode];
#pragma unroll
            for (int rt = 0; rt < 4; ++rt) {
                f32x4 acc = {0.f, 0.f, 0.f, 0.f};
                acc = __builtin_amdgcn_mfma_f32_16x16x32_bf16(afr[rt][0][1], B00, acc, 0, 0, 0);
                acc = __builtin_amdgcn_mfma_f32_16x16x32_bf16(afr[rt][0][0], B01, acc, 0, 0, 0);
                acc = __builtin_amdgcn_mfma_f32_16x16x32_bf16(afr[rt][0][0], B00, acc, 0, 0, 0);
                acc = __builtin_amdgcn_mfma_f32_16x16x32_bf16(afr[rt][1][1], B10, acc, 0, 0, 0);
                acc = __builtin_amdgcn_mfma_f32_16x16x32_bf16(afr[rt][1][0], B11, acc, 0, 0, 0);
                acc = __builtin_amdgcn_mfma_f32_16x16x32_bf16(afr[rt][1][0], B10, acc, 0, 0, 0);
#pragma unroll
                for (int reg = 0; reg < 4; ++reg) {
                    int t = rt * 4 + reg;
                    float d   = __builtin_fmaf(acc[reg], -2.f, en);
                    float d1o = d1[t];
                    d2[t] = __builtin_amdgcn_fmed3f(d, d1o, d2[t]);
                    d1[t] = fminf(d, d1o);
                    i1[t] = (d < d1o) ? mycode : i1[t];
                }
            }
        }
        __syncthreads();   // stage c+1 landed; all waves done reading bufs[c&1]
    }

    // reduce across 16 cols per query row (codes ascend with col: lex-min ok)
#pragma unroll
    for (int t = 0; t < 16; ++t) {
        float a1 = d1[t], a2 = d2[t];
        int ai = i1[t];
#pragma unroll
        for (int off = 1; off < 16; off <<= 1) {
            float o1 = __shfl_xor(a1, off, 64);
            float o2 = __shfl_xor(a2, off, 64);
            int   oi = __shfl_xor(ai, off, 64);
            if (o1 < a1 || (o1 == a1 && oi < ai)) {
                float loser = a1; a2 = fminf(fminf(a2, o2), loser); a1 = o1; ai = oi;
            } else {
                a2 = fminf(fminf(a2, o2), o1);
            }
        }
        d1[t] = a1; d2[t] = a2; i1[t] = ai;
    }

    if (tid == 0) nflag = 0;
    if (col == 0) {
#pragma unroll
        for (int rt = 0; rt < 4; ++rt)
#pragma unroll
            for (int reg = 0; reg < 4; ++reg) {
                int t = rt * 4 + reg;
                int m = w * 64 + rt * 16 + quad * 4 + reg;
                rd1[m] = d1[t];
                rd2[m] = d2[t];
                ri [m] = i1[t];
            }
    }
    __syncthreads();

    // flag queries with margin < TAU for exact in-block re-solve
    if (tid < QT) {
        if (rd2[tid] - rd1[tid] < TAU) {
            int slot = atomicAdd(&nflag, 1);
            flist[slot] = tid;
        }
    }
    __syncthreads();

    // ---- in-block exact fp32 rescue (avg nflag ~1 per block) ----
    for (int f = 0; f < nflag; ++f) {
        const int q = flist[f];
        if (tid < CDIM) xqf[tid] = x[b * (CDIM * HW_SZ) + tid * HW_SZ + hw0 + q];
        __syncthreads();
        float dm = 3.4e38f; int im = 0;
#pragma unroll
        for (int cd = 0; cd < 4; ++cd) {
            const int k = tid + cd * 256;            // codes ascend with cd
            const float4* er = (const float4*)(emb + k * CDIM);
            const float4* xr = (const float4*)xqf;
            float dot = 0.f;
#pragma unroll
            for (int c4 = 0; c4 < 16; ++c4) {
                float4 e = er[c4], xv = xr[c4];
                dot += e.x * xv.x + e.y * xv.y + e.z * xv.z + e.w * xv.w;
            }
            float d = ens[k] - 2.f * dot;            // exact fp32
            if (d < dm) { dm = d; im = k; }
        }
#pragma unroll
        for (int off = 1; off < 64; off <<= 1) {
            float od = __shfl_xor(dm, off, 64);
            int   oi = __shfl_xor(im, off, 64);
            if (od < dm || (od == dm && oi < im)) { dm = od; im = oi; }
        }
        if (lane == 0) { wdd[w] = dm; wii[w] = im; }
        __syncthreads();
        if (tid == 0) {
            float bd = wdd[0]; int bi = wii[0];
#pragma unroll
            for (int ww = 1; ww < 4; ++ww)
                if (wdd[ww] < bd || (wdd[ww] == bd && wii[ww] < bi)) { bd = wdd[ww]; bi = wii[ww]; }
            rd1[q] = bd; ri[q] = bi;                 // final exact result
        }
        __syncthreads();
    }

    // ---- epilogue on FINAL indices: hist, SSE partial ----
    {
        int ai = ri[tid];
        atomicAdd(&hist[ai], 1u);
        float sp = rd1[tid] + xnorm[tid];            // ||q-x||^2 (exact for rescued)
#pragma unroll
        for (int off = 32; off; off >>= 1) sp += __shfl_down(sp, off, 64);
        if (lane == 0) spw[w] = sp;
    }
    __syncthreads();
    if (tid == 0) partials[blockIdx.x] = spw[0] + spw[1] + spw[2] + spw[3];

    // ---- fused output write: four 64-query quarters through the LDS tile ----
#pragma unroll
    for (int h = 0; h < 4; ++h) {
        {   // gather from frag-layout table: thread = (q = tid>>2, j = tid&3)
            int q = tid >> 2, j = tid & 3;
            int code = ri[h * 64 + q];
            int ct = code >> 4, cl = code & 15;
            int kc = j >> 1;
            int qa = (2 * j) & 3, qb = (2 * j + 1) & 3;
            const short* tb = btab + ct * 2048 + kc * 1024;
            short8 hi0 = *(const short8*)&tb[(qa * 16 + cl) * 8];        // dims j*16..+7
            short8 hi1 = *(const short8*)&tb[(qb * 16 + cl) * 8];        // dims j*16+8..+15
            short8 lo0 = *(const short8*)&tb[512 + (qa * 16 + cl) * 8];
            short8 lo1 = *(const short8*)&tb[512 + (qb * 16 + cl) * 8];
            float* dst = &tile[q * 72 + j * 16];
#pragma unroll
            for (int k = 0; k < 8; ++k) {
                dst[k]     = bf2f((unsigned short)hi0[k]) + bf2f((unsigned short)lo0[k]);
                dst[8 + k] = bf2f((unsigned short)hi1[k]) + bf2f((unsigned short)lo1[k]);
            }
        }
        __syncthreads();
        {   // transposed coalesced write
            int c = tid >> 2;
            float* ob = out + b * (CDIM * HW_SZ) + c * HW_SZ + hw0 + h * 64;
#pragma unroll
            for (int p = 0; p < 4; ++p) {
                int q = ((tid & 3) + p * 4) * 4;   // 0..60
                float4 v;
                v.x = tile[(q + 0) * 72 + c];
                v.y = tile[(q + 1) * 72 + c];
                v.z = tile[(q + 2) * 72 + c];
                v.w = tile[(q + 3) * 72 + c];
                *(float4*)&ob[q] = v;
            }
        }
        if (h < 3) __syncthreads();
    }
}

// --------------------------------------------------------------- k_final ----
// 1 block; reads partials (256) + hist (1024) from previous dispatches.
__global__ void k_final(const float* __restrict__ partials,
                        const unsigned int* __restrict__ hist,
                        float* __restrict__ out) {
    int tid = threadIdx.x;   // 256
    float ss = partials[tid];
    float s = 0.f;
#pragma unroll
    for (int i = 0; i < 4; ++i) {
        float p = (float)hist[i * 256 + tid] * (1.0f / 65536.0f);
        s += p * logf(p + 1e-10f);
    }
    __shared__ float fin[8];
#pragma unroll
    for (int off = 32; off; off >>= 1) {
        ss += __shfl_down(ss, off, 64);
        s  += __shfl_down(s, off, 64);
    }
    if ((tid & 63) == 0) { fin[tid >> 6] = ss; fin[4 + (tid >> 6)] = s; }
    __syncthreads();
    if (tid == 0) {
        float sse = fin[0] + fin[1] + fin[2] + fin[3];
        float ent = fin[4] + fin[5] + fin[6] + fin[7];
        out[OUT_ELEMS]     = 1.25f * sse * (1.0f / (float)OUT_ELEMS);  // loss
        out[OUT_ELEMS + 1] = expf(-ent);                                // perplexity
    }
}

// ---------------------------------------------------------------- launch ----
extern "C" void kernel_launch(void* const* d_in, const int* in_sizes, int n_in,
                              void* d_out, int out_size, void* d_ws, size_t ws_size,
                              hipStream_t stream) {
    const float* x   = (const float*)d_in[0];
    const float* emb = (const float*)d_in[1];
    float* out = (float*)d_out;
    char* ws = (char*)d_ws;
    float*        enorm    = (float*)(ws);
    unsigned int* hist     = (unsigned int*)(ws + 4096);
    float*        partials = (float*)(ws + 8192);
    short*        btab     = (short*)(ws + 12288);

    k_prep  <<<64, 256, 0, stream>>>(emb, enorm, btab, hist);
    k_argmin<<<N_TOTAL / QT, 256, 0, stream>>>(x, emb, btab, enorm, hist, partials, out);
    k_final <<<1, 256, 0, stream>>>(partials, hist, out);
}

// Round 4
// 127.076 us; speedup vs baseline: 1.3804x; 1.0414x over previous
//
#include <hip/hip_runtime.h>

// Problem constants
#define N_TOTAL   65536   // B*H*W = 64*32*32
#define HW_SZ     1024    // H*W
#define CDIM      64      // embedding dim (= C)
#define K_CODES   1024
#define OUT_ELEMS 4194304 // 64*64*32*32
#define QT        256     // queries per argmin block (32 per wave, rt=2, 8 waves)
#define NCHUNK    4       // 4 chunks of 256 codes (64 KB each), double-buffered
#define TAU       0.004f  // rescue margin (> 2x analytic bf16x3 error bound ~1.5e-3)

// ws layout (bytes):
//   0      : enorm[1024]   f32
//   4096   : hist[1024]    u32
//   8192   : partials[256] f32
//   12288  : btab (256 KB) bf16 hi/lo table in MFMA B-FRAGMENT order:
//            short index = ct*2048 + kc*1024 + h*512 + lane*8 + j
//            where code = ct*16 + (lane&15), dim = (kc*4 + (lane>>4))*8 + j,
//            h: 0=hi bf16, 1=lo bf16.

typedef __attribute__((ext_vector_type(8))) short short8;
typedef __attribute__((ext_vector_type(4))) float f32x4;

__device__ __forceinline__ unsigned short f2bf(float x) {
    unsigned u = __float_as_uint(x);
    return (unsigned short)((u + 0x7FFFu + ((u >> 16) & 1u)) >> 16);   // RNE
}
__device__ __forceinline__ float bf2f(unsigned short h) {
    return __uint_as_float(((unsigned)h) << 16);
}
__device__ __forceinline__ void gload_lds16(const void* g, void* l) {
    __builtin_amdgcn_global_load_lds(
        (const __attribute__((address_space(1))) void*)g,
        (__attribute__((address_space(3))) void*)l, 16, 0, 0);
}

// ---------------------------------------------------------------- k_prep ----
// Writes ||e||^2 and the frag-ordered bf16 hi/lo table.
__global__ void k_prep(const float* __restrict__ emb, float* __restrict__ enorm,
                       short* __restrict__ btab, unsigned int* __restrict__ hist) {
    int gid = blockIdx.x * 256 + threadIdx.x;        // 0..16383
    int r  = gid >> 4;           // code 0..1023
    int d0 = (gid & 15) * 4;     // dim base 0..60
    float4 v = *(const float4*)(emb + gid * 4);
    float s = v.x * v.x + v.y * v.y + v.z * v.z + v.w * v.w;
#pragma unroll
    for (int off = 1; off < 16; off <<= 1) s += __shfl_xor(s, off, 64);
    if ((gid & 15) == 0) enorm[r] = s;

    float vv[4] = {v.x, v.y, v.z, v.w};
    short h[4], l[4];
#pragma unroll
    for (int j = 0; j < 4; ++j) {
        unsigned short hh = f2bf(vv[j]);
        h[j] = (short)hh;
        l[j] = (short)f2bf(vv[j] - bf2f(hh));
    }
    // frag-layout destination (see ws comment). d0..d0+3 stay in one 8-dim group.
    int base = (r >> 4) * 2048 + (d0 >> 5) * 1024
             + ((((d0 >> 3) & 3) * 16 + (r & 15)) * 8) + (d0 & 7);
    *(short4*)&btab[base]       = make_short4(h[0], h[1], h[2], h[3]);
    *(short4*)&btab[base + 512] = make_short4(l[0], l[1], l[2], l[3]);

    if (gid < K_CODES) hist[gid] = 0u;
}

// -------------------------------------------------------------- k_argmin ----
// 512 thr = 8 waves (2 waves/SIMD for cross-wave latency hiding); QT=256
// queries/block, 2 query-tiles of 16 per wave. Code table is LDS-RESIDENT in
// 4 double-buffered chunks of 256 codes (64 KB). Per code-tile: two
// INDEPENDENT 3-deep MFMA chains (one per kc half, fp32-summed) -> 4 chains
// per wave, 8 per SIMD. bf16x3 distance, top-2 tracking, TAU-margin exact
// fp32 in-block rescue, fused epilogue.
__global__ __launch_bounds__(512, 2)
void k_argmin(const float* __restrict__ x, const float* __restrict__ emb,
              const short* __restrict__ btab, const float* __restrict__ enorm,
              unsigned int* __restrict__ hist, float* __restrict__ partials,
              float* __restrict__ out) {
    __shared__ __align__(16) short bufs[2][16 * 2048];   // 2 x 64 KB chunk buffers
    __shared__ __align__(16) float ens[K_CODES];         // 4 KB exact fp32 ||e||^2
    __shared__ float xnorm[QT];
    __shared__ float rd1[QT];
    __shared__ float rd2[QT];
    __shared__ int   ri[QT];
    __shared__ int   flist[QT];
    __shared__ __align__(16) float xqf[CDIM];
    __shared__ float wdd[8];
    __shared__ int   wii[8];
    __shared__ float spw[4];
    __shared__ int   nflag;
    float* tile = (float*)bufs;      // 64*72 f32 epilogue transpose, aliases bufs

    const int tid  = threadIdx.x;
    const int lane = tid & 63;
    const int w    = tid >> 6;       // 0..7
    const int quad = lane >> 4;
    const int col  = lane & 15;

    const int n0  = blockIdx.x * QT;
    const int b   = n0 >> 10;
    const int hw0 = n0 & 1023;        // 256-aligned

    auto stage_async = [&](int c, int bsel) {
        const short* src = btab + c * (16 * 2048);
#pragma unroll
        for (int i = 0; i < 8; ++i) {
            int idx = i * 512 + tid;                  // 16B units, 0..4095
            gload_lds16(&src[idx * 8], (void*)&bufs[bsel][idx * 8]);
        }
    };

    // kick off chunk 0 + ||e||^2 while we build A-fragments in registers
    stage_async(0, 0);
    if (tid < 256) gload_lds16(&enorm[tid * 4], (void*)&ens[tid * 4]);

    // A fragments straight from global; hi/lo bf16 split in regs; ||x||^2 via shfl.
    const float* xb = x + b * (CDIM * HW_SZ) + hw0 + col;
    short8 afr[2][2][2];     // [rt][kc][hi/lo]
#pragma unroll
    for (int rt = 0; rt < 2; ++rt) {
        float nloc = 0.f;
#pragma unroll
        for (int kc = 0; kc < 2; ++kc) {
#pragma unroll
            for (int j = 0; j < 8; ++j) {
                int c0 = (kc * 4 + quad) * 8 + j;
                float v = xb[c0 * HW_SZ + w * 32 + rt * 16];
                unsigned short hh = f2bf(v);
                afr[rt][kc][0][j] = (short)hh;
                afr[rt][kc][1][j] = (short)f2bf(v - bf2f(hh));
                nloc = __builtin_fmaf(v, v, nloc);
            }
        }
        nloc += __shfl_xor(nloc, 16, 64);
        nloc += __shfl_xor(nloc, 32, 64);
        if (quad == 0) xnorm[w * 32 + rt * 16 + col] = nloc;
    }

    float d1[8], d2[8];
    int   i1[8];
#pragma unroll
    for (int t = 0; t < 8; ++t) { d1[t] = 3.4e38f; d2[t] = 3.4e38f; i1[t] = 0; }

    __syncthreads();   // chunk 0 + ens + xnorm ready

    for (int c = 0; c < NCHUNK; ++c) {
        if (c + 1 < NCHUNK) stage_async(c + 1, (c + 1) & 1);   // other buffer is free
        const short* bs = &bufs[c & 1][0];
        const int cbase = c * 256;
#pragma unroll 4
        for (int ctl = 0; ctl < 16; ++ctl) {
            const short* fp = bs + ctl * 2048 + lane * 8;
            short8 B00 = *(const short8*)(fp);            // kc0 hi
            short8 B01 = *(const short8*)(fp + 512);      // kc0 lo
            short8 B10 = *(const short8*)(fp + 1024);     // kc1 hi
            short8 B11 = *(const short8*)(fp + 1536);     // kc1 lo
            const int   mycode = cbase + ctl * 16 + col;
            const float en     = ens[mycode];
#pragma unroll
            for (int rt = 0; rt < 2; ++rt) {
                // two independent 3-deep chains (kc0, kc1), fp32-summed
                f32x4 a0 = {0.f, 0.f, 0.f, 0.f};
                f32x4 a1 = {0.f, 0.f, 0.f, 0.f};
                a0 = __builtin_amdgcn_mfma_f32_16x16x32_bf16(afr[rt][0][1], B00, a0, 0, 0, 0);
                a1 = __builtin_amdgcn_mfma_f32_16x16x32_bf16(afr[rt][1][1], B10, a1, 0, 0, 0);
                a0 = __builtin_amdgcn_mfma_f32_16x16x32_bf16(afr[rt][0][0], B01, a0, 0, 0, 0);
                a1 = __builtin_amdgcn_mfma_f32_16x16x32_bf16(afr[rt][1][0], B11, a1, 0, 0, 0);
                a0 = __builtin_amdgcn_mfma_f32_16x16x32_bf16(afr[rt][0][0], B00, a0, 0, 0, 0);
                a1 = __builtin_amdgcn_mfma_f32_16x16x32_bf16(afr[rt][1][0], B10, a1, 0, 0, 0);
#pragma unroll
                for (int reg = 0; reg < 4; ++reg) {
                    int t = rt * 4 + reg;
                    float dot = a0[reg] + a1[reg];
                    float d   = __builtin_fmaf(dot, -2.f, en);
                    float d1o = d1[t];
                    d2[t] = __builtin_amdgcn_fmed3f(d, d1o, d2[t]);
                    d1[t] = fminf(d, d1o);
                    i1[t] = (d < d1o) ? mycode : i1[t];
                }
            }
        }
        __syncthreads();   // stage c+1 landed; all waves done reading bufs[c&1]
    }

    // reduce across 16 cols per query row (codes ascend with col: lex-min ok)
#pragma unroll
    for (int t = 0; t < 8; ++t) {
        float a1 = d1[t], a2 = d2[t];
        int ai = i1[t];
#pragma unroll
        for (int off = 1; off < 16; off <<= 1) {
            float o1 = __shfl_xor(a1, off, 64);
            float o2 = __shfl_xor(a2, off, 64);
            int   oi = __shfl_xor(ai, off, 64);
            if (o1 < a1 || (o1 == a1 && oi < ai)) {
                float loser = a1; a2 = fminf(fminf(a2, o2), loser); a1 = o1; ai = oi;
            } else {
                a2 = fminf(fminf(a2, o2), o1);
            }
        }
        d1[t] = a1; d2[t] = a2; i1[t] = ai;
    }

    if (tid == 0) nflag = 0;
    if (col == 0) {
#pragma unroll
        for (int rt = 0; rt < 2; ++rt)
#pragma unroll
            for (int reg = 0; reg < 4; ++reg) {
                int t = rt * 4 + reg;
                int m = w * 32 + rt * 16 + quad * 4 + reg;
                rd1[m] = d1[t];
                rd2[m] = d2[t];
                ri [m] = i1[t];
            }
    }
    __syncthreads();

    // flag queries with margin < TAU for exact in-block re-solve
    if (tid < QT) {
        if (rd2[tid] - rd1[tid] < TAU) {
            int slot = atomicAdd(&nflag, 1);
            flist[slot] = tid;
        }
    }
    __syncthreads();

    // ---- in-block exact fp32 rescue (avg nflag ~1 per block) ----
    for (int f = 0; f < nflag; ++f) {
        const int q = flist[f];
        if (tid < CDIM) xqf[tid] = x[b * (CDIM * HW_SZ) + tid * HW_SZ + hw0 + q];
        __syncthreads();
        float dm = 3.4e38f; int im = 0;
#pragma unroll
        for (int cd = 0; cd < 2; ++cd) {
            const int k = tid + cd * 512;            // codes ascend with cd
            const float4* er = (const float4*)(emb + k * CDIM);
            const float4* xr = (const float4*)xqf;
            float dot = 0.f;
#pragma unroll
            for (int c4 = 0; c4 < 16; ++c4) {
                float4 e = er[c4], xv = xr[c4];
                dot += e.x * xv.x + e.y * xv.y + e.z * xv.z + e.w * xv.w;
            }
            float d = ens[k] - 2.f * dot;            // exact fp32
            if (d < dm) { dm = d; im = k; }
        }
#pragma unroll
        for (int off = 1; off < 64; off <<= 1) {
            float od = __shfl_xor(dm, off, 64);
            int   oi = __shfl_xor(im, off, 64);
            if (od < dm || (od == dm && oi < im)) { dm = od; im = oi; }
        }
        if (lane == 0) { wdd[w] = dm; wii[w] = im; }
        __syncthreads();
        if (tid == 0) {
            float bd = wdd[0]; int bi = wii[0];
#pragma unroll
            for (int ww = 1; ww < 8; ++ww)
                if (wdd[ww] < bd || (wdd[ww] == bd && wii[ww] < bi)) { bd = wdd[ww]; bi = wii[ww]; }
            rd1[q] = bd; ri[q] = bi;                 // final exact result
        }
        __syncthreads();
    }

    // ---- epilogue on FINAL indices: hist, SSE partial (first 4 waves) ----
    if (tid < QT) {
        int ai = ri[tid];
        atomicAdd(&hist[ai], 1u);
        float sp = rd1[tid] + xnorm[tid];            // ||q-x||^2 (exact for rescued)
#pragma unroll
        for (int off = 32; off; off >>= 1) sp += __shfl_down(sp, off, 64);
        if (lane == 0) spw[w] = sp;
    }
    __syncthreads();
    if (tid == 0) partials[blockIdx.x] = spw[0] + spw[1] + spw[2] + spw[3];

    // ---- fused output write: four 64-query quarters through the LDS tile ----
#pragma unroll
    for (int h = 0; h < 4; ++h) {
        {   // gather from frag-layout table: thread = (q = tid>>3, j8 = tid&7)
            int q = tid >> 3, j8 = tid & 7;          // 8 dims per thread
            int code = ri[h * 64 + q];
            int ct = code >> 4, cl = code & 15;
            int kc = j8 >> 2, qd = j8 & 3;
            const short* tb = btab + ct * 2048 + kc * 1024;
            short8 hi = *(const short8*)&tb[(qd * 16 + cl) * 8];
            short8 lo = *(const short8*)&tb[512 + (qd * 16 + cl) * 8];
            float* dst = &tile[q * 72 + j8 * 8];
#pragma unroll
            for (int k = 0; k < 8; ++k)
                dst[k] = bf2f((unsigned short)hi[k]) + bf2f((unsigned short)lo[k]);
        }
        __syncthreads();
        {   // transposed coalesced write
            int c = tid >> 3;
            float* ob = out + b * (CDIM * HW_SZ) + c * HW_SZ + hw0 + h * 64;
#pragma unroll
            for (int p = 0; p < 2; ++p) {
                int q = ((tid & 7) + p * 8) * 4;   // 0..60
                float4 v;
                v.x = tile[(q + 0) * 72 + c];
                v.y = tile[(q + 1) * 72 + c];
                v.z = tile[(q + 2) * 72 + c];
                v.w = tile[(q + 3) * 72 + c];
                *(float4*)&ob[q] = v;
            }
        }
        if (h < 3) __syncthreads();
    }
}

// --------------------------------------------------------------- k_final ----
// 1 block; reads partials (256) + hist (1024) from previous dispatches.
__global__ void k_final(const float* __restrict__ partials,
                        const unsigned int* __restrict__ hist,
                        float* __restrict__ out) {
    int tid = threadIdx.x;   // 256
    float ss = partials[tid];
    float s = 0.f;
#pragma unroll
    for (int i = 0; i < 4; ++i) {
        float p = (float)hist[i * 256 + tid] * (1.0f / 65536.0f);
        s += p * logf(p + 1e-10f);
    }
    __shared__ float fin[8];
#pragma unroll
    for (int off = 32; off; off >>= 1) {
        ss += __shfl_down(ss, off, 64);
        s  += __shfl_down(s, off, 64);
    }
    if ((tid & 63) == 0) { fin[tid >> 6] = ss; fin[4 + (tid >> 6)] = s; }
    __syncthreads();
    if (tid == 0) {
        float sse = fin[0] + fin[1] + fin[2] + fin[3];
        float ent = fin[4] + fin[5] + fin[6] + fin[7];
        out[OUT_ELEMS]     = 1.25f * sse * (1.0f / (float)OUT_ELEMS);  // loss
        out[OUT_ELEMS + 1] = expf(-ent);                                // perplexity
    }
}

// ---------------------------------------------------------------- launch ----
extern "C" void kernel_launch(void* const* d_in, const int* in_sizes, int n_in,
                              void* d_out, int out_size, void* d_ws, size_t ws_size,
                              hipStream_t stream) {
    const float* x   = (const float*)d_in[0];
    const float* emb = (const float*)d_in[1];
    float* out = (float*)d_out;
    char* ws = (char*)d_ws;
    float*        enorm    = (float*)(ws);
    unsigned int* hist     = (unsigned int*)(ws + 4096);
    float*        partials = (float*)(ws + 8192);
    short*        btab     = (short*)(ws + 12288);

    k_prep  <<<64, 256, 0, stream>>>(emb, enorm, btab, hist);
    k_argmin<<<N_TOTAL / QT, 512, 0, stream>>>(x, emb, btab, enorm, hist, partials, out);
    k_final <<<1, 256, 0, stream>>>(partials, hist, out);
}

// Round 5
// 124.241 us; speedup vs baseline: 1.4119x; 1.0228x over previous
//
#include <hip/hip_runtime.h>

// Problem constants
#define N_TOTAL   65536   // B*H*W = 64*32*32
#define HW_SZ     1024    // H*W
#define CDIM      64      // embedding dim (= C)
#define K_CODES   1024
#define OUT_ELEMS 4194304 // 64*64*32*32
#define QT        256     // queries per argmin block (32 per wave, rt=2, 8 waves)
#define NCHUNK    4       // 4 chunks of 256 codes (64 KB each), double-buffered
#define TAU       0.004f  // rescue margin (> 2x analytic bf16x3 error bound ~1.5e-3)

// ws layout (bytes):
//   0      : enorm[1024]   f32
//   4096   : hist[1024]    u32
//   8192   : partials[256] f32
//   12288  : btab (256 KB) bf16 hi/lo table in MFMA B-FRAGMENT order:
//            short index = ct*2048 + kc*1024 + h*512 + lane*8 + j
//            where code = ct*16 + (lane&15), dim = (kc*4 + (lane>>4))*8 + j,
//            h: 0=hi bf16, 1=lo bf16.

typedef __attribute__((ext_vector_type(8))) short short8;
typedef __attribute__((ext_vector_type(4))) float f32x4;

__device__ __forceinline__ unsigned short f2bf(float x) {
    unsigned u = __float_as_uint(x);
    return (unsigned short)((u + 0x7FFFu + ((u >> 16) & 1u)) >> 16);   // RNE
}
__device__ __forceinline__ float bf2f(unsigned short h) {
    return __uint_as_float(((unsigned)h) << 16);
}
__device__ __forceinline__ void gload_lds16(const void* g, void* l) {
    __builtin_amdgcn_global_load_lds(
        (const __attribute__((address_space(1))) void*)g,
        (__attribute__((address_space(3))) void*)l, 16, 0, 0);
}

// ---------------------------------------------------------------- k_prep ----
// Writes ||e||^2 and the frag-ordered bf16 hi/lo table.
__global__ void k_prep(const float* __restrict__ emb, float* __restrict__ enorm,
                       short* __restrict__ btab, unsigned int* __restrict__ hist) {
    int gid = blockIdx.x * 256 + threadIdx.x;        // 0..16383
    int r  = gid >> 4;           // code 0..1023
    int d0 = (gid & 15) * 4;     // dim base 0..60
    float4 v = *(const float4*)(emb + gid * 4);
    float s = v.x * v.x + v.y * v.y + v.z * v.z + v.w * v.w;
#pragma unroll
    for (int off = 1; off < 16; off <<= 1) s += __shfl_xor(s, off, 64);
    if ((gid & 15) == 0) enorm[r] = s;

    float vv[4] = {v.x, v.y, v.z, v.w};
    short h[4], l[4];
#pragma unroll
    for (int j = 0; j < 4; ++j) {
        unsigned short hh = f2bf(vv[j]);
        h[j] = (short)hh;
        l[j] = (short)f2bf(vv[j] - bf2f(hh));
    }
    // frag-layout destination (see ws comment). d0..d0+3 stay in one 8-dim group.
    int base = (r >> 4) * 2048 + (d0 >> 5) * 1024
             + ((((d0 >> 3) & 3) * 16 + (r & 15)) * 8) + (d0 & 7);
    *(short4*)&btab[base]       = make_short4(h[0], h[1], h[2], h[3]);
    *(short4*)&btab[base + 512] = make_short4(l[0], l[1], l[2], l[3]);

    if (gid < K_CODES) hist[gid] = 0u;
}

// -------------------------------------------------------------- k_argmin ----
// 512 thr = 8 waves (2/SIMD); QT=256 queries/block, 2 query-tiles of 16 per
// wave. Code table LDS-RESIDENT in 4 double-buffered chunks of 256 codes.
// K-loop is an EXPLICIT 2-stage register pipeline: B-fragments (+ en scalar)
// for ctl+1 are ds_read-issued BEFORE ctl's MFMA/min-update consumes Ba, with
// named register sets Ba/Bb (static indexing). Fully unrolled so all offsets
// are immediates. bf16x3 distance via two independent 3-deep MFMA chains,
// top-2 tracking, TAU-margin exact fp32 in-block rescue, fused epilogue.
__global__ __launch_bounds__(512, 2)
void k_argmin(const float* __restrict__ x, const float* __restrict__ emb,
              const short* __restrict__ btab, const float* __restrict__ enorm,
              unsigned int* __restrict__ hist, float* __restrict__ partials,
              float* __restrict__ out) {
    __shared__ __align__(16) short bufs[2][16 * 2048];   // 2 x 64 KB chunk buffers
    __shared__ __align__(16) float ens[K_CODES];         // 4 KB exact fp32 ||e||^2
    __shared__ float xnorm[QT];
    __shared__ float rd1[QT];
    __shared__ float rd2[QT];
    __shared__ int   ri[QT];
    __shared__ int   flist[QT];
    __shared__ __align__(16) float xqf[CDIM];
    __shared__ float wdd[8];
    __shared__ int   wii[8];
    __shared__ float spw[4];
    __shared__ int   nflag;
    float* tile = (float*)bufs;      // 64*72 f32 epilogue transpose, aliases bufs

    const int tid  = threadIdx.x;
    const int lane = tid & 63;
    const int w    = tid >> 6;       // 0..7
    const int quad = lane >> 4;
    const int col  = lane & 15;

    const int n0  = blockIdx.x * QT;
    const int b   = n0 >> 10;
    const int hw0 = n0 & 1023;        // 256-aligned

    auto stage_async = [&](int c, int bsel) {
        const short* src = btab + c * (16 * 2048);
#pragma unroll
        for (int i = 0; i < 8; ++i) {
            int idx = i * 512 + tid;                  // 16B units, 0..4095
            gload_lds16(&src[idx * 8], (void*)&bufs[bsel][idx * 8]);
        }
    };

    // kick off chunk 0 + ||e||^2 while we build A-fragments in registers
    stage_async(0, 0);
    if (tid < 256) gload_lds16(&enorm[tid * 4], (void*)&ens[tid * 4]);

    // A fragments straight from global; hi/lo bf16 split in regs; ||x||^2 via shfl.
    const float* xb = x + b * (CDIM * HW_SZ) + hw0 + col;
    short8 afr[2][2][2];     // [rt][kc][hi/lo]
#pragma unroll
    for (int rt = 0; rt < 2; ++rt) {
        float nloc = 0.f;
#pragma unroll
        for (int kc = 0; kc < 2; ++kc) {
#pragma unroll
            for (int j = 0; j < 8; ++j) {
                int c0 = (kc * 4 + quad) * 8 + j;
                float v = xb[c0 * HW_SZ + w * 32 + rt * 16];
                unsigned short hh = f2bf(v);
                afr[rt][kc][0][j] = (short)hh;
                afr[rt][kc][1][j] = (short)f2bf(v - bf2f(hh));
                nloc = __builtin_fmaf(v, v, nloc);
            }
        }
        nloc += __shfl_xor(nloc, 16, 64);
        nloc += __shfl_xor(nloc, 32, 64);
        if (quad == 0) xnorm[w * 32 + rt * 16 + col] = nloc;
    }

    float d1[8], d2[8];
    int   i1[8];
#pragma unroll
    for (int t = 0; t < 8; ++t) { d1[t] = 3.4e38f; d2[t] = 3.4e38f; i1[t] = 0; }

    __syncthreads();   // chunk 0 + ens + xnorm ready

    for (int c = 0; c < NCHUNK; ++c) {
        if (c + 1 < NCHUNK) stage_async(c + 1, (c + 1) & 1);   // other buffer is free
        const short* bs = &bufs[c & 1][0];
        const int cbase = c * 256;

        // explicit 2-stage register pipeline over the 16 code-tiles
        short8 Ba[4], Bb[4];          // [kc0hi, kc0lo, kc1hi, kc1lo]
        float  ena, enb;
        auto LDB = [&](short8 (&B)[4], float& en, int ctl) {
            const short* fp = bs + ctl * 2048 + lane * 8;
            B[0] = *(const short8*)(fp);            // kc0 hi
            B[1] = *(const short8*)(fp + 512);      // kc0 lo
            B[2] = *(const short8*)(fp + 1024);     // kc1 hi
            B[3] = *(const short8*)(fp + 1536);     // kc1 lo
            en   = ens[cbase + ctl * 16 + col];
        };
        auto COMP = [&](const short8 (&B)[4], float en, int mycode) {
#pragma unroll
            for (int rt = 0; rt < 2; ++rt) {
                // two independent 3-deep chains (kc0, kc1), fp32-summed
                f32x4 a0 = {0.f, 0.f, 0.f, 0.f};
                f32x4 a1 = {0.f, 0.f, 0.f, 0.f};
                a0 = __builtin_amdgcn_mfma_f32_16x16x32_bf16(afr[rt][0][1], B[0], a0, 0, 0, 0);
                a1 = __builtin_amdgcn_mfma_f32_16x16x32_bf16(afr[rt][1][1], B[2], a1, 0, 0, 0);
                a0 = __builtin_amdgcn_mfma_f32_16x16x32_bf16(afr[rt][0][0], B[1], a0, 0, 0, 0);
                a1 = __builtin_amdgcn_mfma_f32_16x16x32_bf16(afr[rt][1][0], B[3], a1, 0, 0, 0);
                a0 = __builtin_amdgcn_mfma_f32_16x16x32_bf16(afr[rt][0][0], B[0], a0, 0, 0, 0);
                a1 = __builtin_amdgcn_mfma_f32_16x16x32_bf16(afr[rt][1][0], B[2], a1, 0, 0, 0);
#pragma unroll
                for (int reg = 0; reg < 4; ++reg) {
                    int t = rt * 4 + reg;
                    float dot = a0[reg] + a1[reg];
                    float d   = __builtin_fmaf(dot, -2.f, en);
                    float d1o = d1[t];
                    d2[t] = __builtin_amdgcn_fmed3f(d, d1o, d2[t]);
                    d1[t] = fminf(d, d1o);
                    i1[t] = (d < d1o) ? mycode : i1[t];
                }
            }
        };

        LDB(Ba, ena, 0);
#pragma unroll
        for (int ctl = 0; ctl < 16; ctl += 2) {
            LDB(Bb, enb, ctl + 1);                     // prefetch odd tile
            COMP(Ba, ena, cbase + ctl * 16 + col);     // consume even tile
            if (ctl + 2 < 16) LDB(Ba, ena, ctl + 2);   // prefetch next even tile
            COMP(Bb, enb, cbase + (ctl + 1) * 16 + col);
        }
        __syncthreads();   // stage c+1 landed; all waves done reading bufs[c&1]
    }

    // reduce across 16 cols per query row (codes ascend with col: lex-min ok)
#pragma unroll
    for (int t = 0; t < 8; ++t) {
        float a1 = d1[t], a2 = d2[t];
        int ai = i1[t];
#pragma unroll
        for (int off = 1; off < 16; off <<= 1) {
            float o1 = __shfl_xor(a1, off, 64);
            float o2 = __shfl_xor(a2, off, 64);
            int   oi = __shfl_xor(ai, off, 64);
            if (o1 < a1 || (o1 == a1 && oi < ai)) {
                float loser = a1; a2 = fminf(fminf(a2, o2), loser); a1 = o1; ai = oi;
            } else {
                a2 = fminf(fminf(a2, o2), o1);
            }
        }
        d1[t] = a1; d2[t] = a2; i1[t] = ai;
    }

    if (tid == 0) nflag = 0;
    if (col == 0) {
#pragma unroll
        for (int rt = 0; rt < 2; ++rt)
#pragma unroll
            for (int reg = 0; reg < 4; ++reg) {
                int t = rt * 4 + reg;
                int m = w * 32 + rt * 16 + quad * 4 + reg;
                rd1[m] = d1[t];
                rd2[m] = d2[t];
                ri [m] = i1[t];
            }
    }
    __syncthreads();

    // flag queries with margin < TAU for exact in-block re-solve
    if (tid < QT) {
        if (rd2[tid] - rd1[tid] < TAU) {
            int slot = atomicAdd(&nflag, 1);
            flist[slot] = tid;
        }
    }
    __syncthreads();

    // ---- in-block exact fp32 rescue (avg nflag ~1 per block) ----
    for (int f = 0; f < nflag; ++f) {
        const int q = flist[f];
        if (tid < CDIM) xqf[tid] = x[b * (CDIM * HW_SZ) + tid * HW_SZ + hw0 + q];
        __syncthreads();
        float dm = 3.4e38f; int im = 0;
#pragma unroll
        for (int cd = 0; cd < 2; ++cd) {
            const int k = tid + cd * 512;            // codes ascend with cd
            const float4* er = (const float4*)(emb + k * CDIM);
            const float4* xr = (const float4*)xqf;
            float dot = 0.f;
#pragma unroll
            for (int c4 = 0; c4 < 16; ++c4) {
                float4 e = er[c4], xv = xr[c4];
                dot += e.x * xv.x + e.y * xv.y + e.z * xv.z + e.w * xv.w;
            }
            float d = ens[k] - 2.f * dot;            // exact fp32
            if (d < dm) { dm = d; im = k; }
        }
#pragma unroll
        for (int off = 1; off < 64; off <<= 1) {
            float od = __shfl_xor(dm, off, 64);
            int   oi = __shfl_xor(im, off, 64);
            if (od < dm || (od == dm && oi < im)) { dm = od; im = oi; }
        }
        if (lane == 0) { wdd[w] = dm; wii[w] = im; }
        __syncthreads();
        if (tid == 0) {
            float bd = wdd[0]; int bi = wii[0];
#pragma unroll
            for (int ww = 1; ww < 8; ++ww)
                if (wdd[ww] < bd || (wdd[ww] == bd && wii[ww] < bi)) { bd = wdd[ww]; bi = wii[ww]; }
            rd1[q] = bd; ri[q] = bi;                 // final exact result
        }
        __syncthreads();
    }

    // ---- epilogue on FINAL indices: hist, SSE partial (first 4 waves) ----
    if (tid < QT) {
        int ai = ri[tid];
        atomicAdd(&hist[ai], 1u);
        float sp = rd1[tid] + xnorm[tid];            // ||q-x||^2 (exact for rescued)
#pragma unroll
        for (int off = 32; off; off >>= 1) sp += __shfl_down(sp, off, 64);
        if (lane == 0) spw[w] = sp;
    }
    __syncthreads();
    if (tid == 0) partials[blockIdx.x] = spw[0] + spw[1] + spw[2] + spw[3];

    // ---- fused output write: four 64-query quarters through the LDS tile ----
#pragma unroll
    for (int h = 0; h < 4; ++h) {
        {   // gather from frag-layout table: thread = (q = tid>>3, j8 = tid&7)
            int q = tid >> 3, j8 = tid & 7;          // 8 dims per thread
            int code = ri[h * 64 + q];
            int ct = code >> 4, cl = code & 15;
            int kc = j8 >> 2, qd = j8 & 3;
            const short* tb = btab + ct * 2048 + kc * 1024;
            short8 hi = *(const short8*)&tb[(qd * 16 + cl) * 8];
            short8 lo = *(const short8*)&tb[512 + (qd * 16 + cl) * 8];
            float* dst = &tile[q * 72 + j8 * 8];
#pragma unroll
            for (int k = 0; k < 8; ++k)
                dst[k] = bf2f((unsigned short)hi[k]) + bf2f((unsigned short)lo[k]);
        }
        __syncthreads();
        {   // transposed coalesced write
            int c = tid >> 3;
            float* ob = out + b * (CDIM * HW_SZ) + c * HW_SZ + hw0 + h * 64;
#pragma unroll
            for (int p = 0; p < 2; ++p) {
                int q = ((tid & 7) + p * 8) * 4;   // 0..60
                float4 v;
                v.x = tile[(q + 0) * 72 + c];
                v.y = tile[(q + 1) * 72 + c];
                v.z = tile[(q + 2) * 72 + c];
                v.w = tile[(q + 3) * 72 + c];
                *(float4*)&ob[q] = v;
            }
        }
        if (h < 3) __syncthreads();
    }
}

// --------------------------------------------------------------- k_final ----
// 1 block; reads partials (256) + hist (1024) from previous dispatches.
__global__ void k_final(const float* __restrict__ partials,
                        const unsigned int* __restrict__ hist,
                        float* __restrict__ out) {
    int tid = threadIdx.x;   // 256
    float ss = partials[tid];
    float s = 0.f;
#pragma unroll
    for (int i = 0; i < 4; ++i) {
        float p = (float)hist[i * 256 + tid] * (1.0f / 65536.0f);
        s += p * logf(p + 1e-10f);
    }
    __shared__ float fin[8];
#pragma unroll
    for (int off = 32; off; off >>= 1) {
        ss += __shfl_down(ss, off, 64);
        s  += __shfl_down(s, off, 64);
    }
    if ((tid & 63) == 0) { fin[tid >> 6] = ss; fin[4 + (tid >> 6)] = s; }
    __syncthreads();
    if (tid == 0) {
        float sse = fin[0] + fin[1] + fin[2] + fin[3];
        float ent = fin[4] + fin[5] + fin[6] + fin[7];
        out[OUT_ELEMS]     = 1.25f * sse * (1.0f / (float)OUT_ELEMS);  // loss
        out[OUT_ELEMS + 1] = expf(-ent);                                // perplexity
    }
}

// ---------------------------------------------------------------- launch ----
extern "C" void kernel_launch(void* const* d_in, const int* in_sizes, int n_in,
                              void* d_out, int out_size, void* d_ws, size_t ws_size,
                              hipStream_t stream) {
    const float* x   = (const float*)d_in[0];
    const float* emb = (const float*)d_in[1];
    float* out = (float*)d_out;
    char* ws = (char*)d_ws;
    float*        enorm    = (float*)(ws);
    unsigned int* hist     = (unsigned int*)(ws + 4096);
    float*        partials = (float*)(ws + 8192);
    short*        btab     = (short*)(ws + 12288);

    k_prep  <<<64, 256, 0, stream>>>(emb, enorm, btab, hist);
    k_argmin<<<N_TOTAL / QT, 512, 0, stream>>>(x, emb, btab, enorm, hist, partials, out);
    k_final <<<1, 256, 0, stream>>>(partials, hist, out);
}